// Round 2
// baseline (294.118 us; speedup 1.0000x reference)
//
#include <hip/hip_runtime.h>

// PolynomialKernel: per row of 128 fp32 values:
//   x_norm = x / max(||x||_2, 1e-12)
//   out[0:128]    = x_norm
//   out[128:8384] = triu(i<=j) products x_norm[i]*x_norm[j] * degree_scales[1]
// Rows = B*L = 8192. Output row stride 8384 fp32.
//
// Strategy: build the whole output row in a 33.5 KB LDS image.
//  - Phase 1a: wave 0 loads the row (float4), wave-reduces ||x||, writes
//    x_norm into img[0:128].
//  - Phase 1b: triangle-run parallelism. Wave w handles runs i = w, w+4, ...
//    Within a run, img[i] is a wave-uniform broadcast (no conflict) and
//    img[i+l] is lane-stride-1 (2 lanes/bank = free). No index decode,
//    no divergent branches.
//  - Phase 2: stream img -> global as aligned float4 (the write-BW-bound
//    part, kept textbook-coalesced).

#define DD 128
#define ROW_OUT (DD + DD * (DD + 1) / 2) /* 8384 */
#define NCHUNK (ROW_OUT / 4)             /* 2096 */

__global__ __launch_bounds__(256) void poly_kernel(
    const float* __restrict__ x, const float* __restrict__ scales,
    float* __restrict__ out) {
  __shared__ float s_img[ROW_OUT];  // 33536 B -> 4 blocks/CU

  const int row = blockIdx.x;
  const int tid = threadIdx.x;
  const float s1 = scales[1];

  // ---- Phase 1a: load + normalize (wave 0 only) ----
  if (tid < 64) {
    float4 xv = make_float4(0.f, 0.f, 0.f, 0.f);
    if (tid < 32) xv = ((const float4*)(x + (size_t)row * DD))[tid];
    float partial = xv.x * xv.x + xv.y * xv.y + xv.z * xv.z + xv.w * xv.w;
#pragma unroll
    for (int off = 16; off >= 1; off >>= 1)
      partial += __shfl_down(partial, off, 64);
    float total = __shfl(partial, 0, 64);  // lane 0 holds the sum
    float inv = 1.0f / fmaxf(sqrtf(total), 1e-12f);
    if (tid < 32)
      ((float4*)s_img)[tid] =
          make_float4(xv.x * inv, xv.y * inv, xv.z * inv, xv.w * inv);
  }
  __syncthreads();

  // ---- Phase 1b: fill img[128:8384] with scaled pair products ----
  const int w = tid >> 6;    // wave id 0..3
  const int lane = tid & 63; // lane in wave
  for (int i = w; i < DD; i += 4) {
    const float xi = s_img[i] * s1;                 // broadcast read
    const int len = DD - i;
    const int base = DD + ((i * (2 * DD + 1 - i)) >> 1);
    for (int l = lane; l < len; l += 64)
      s_img[base + l] = xi * s_img[i + l];          // stride-1 read/write
  }
  __syncthreads();

  // ---- Phase 2: stream to global, aligned float4 ----
  float* orow = out + (size_t)row * ROW_OUT;
  for (int p4 = tid; p4 < NCHUNK; p4 += 256)
    ((float4*)orow)[p4] = ((const float4*)s_img)[p4];
}

extern "C" void kernel_launch(void* const* d_in, const int* in_sizes, int n_in,
                              void* d_out, int out_size, void* d_ws,
                              size_t ws_size, hipStream_t stream) {
  const float* x = (const float*)d_in[0];
  const float* scales = (const float*)d_in[1];
  float* out = (float*)d_out;
  const int n_rows = in_sizes[0] / DD;  // 8192
  poly_kernel<<<n_rows, 256, 0, stream>>>(x, scales, out);
}

// Round 3
// 282.802 us; speedup vs baseline: 1.0400x; 1.0400x over previous
//
#include <hip/hip_runtime.h>

// PolynomialKernel: per row of 128 fp32 values:
//   x_norm = x / max(||x||_2, 1e-12)
//   out[0:128]    = x_norm
//   out[128:8384] = triu(i<=j) products x_norm[i]*x_norm[j] * degree_scales[1]
// Rows = B*L = 8192. Output row stride 8384 fp32 = 33536 B (128B-line aligned).
//
// Round-3 design: run-mapped direct stores.
//  - Each of 4 waves redundantly loads the 128-float row (L1/L2 dedup),
//    butterfly-reduces ||x||^2 -> every lane holds c1, c2. One barrier only
//    (for the s_x staging write).
//  - Wave w handles triangle runs i = w, w+4, ... (balanced: ~2064 elems
//    per wave). Per run: x[i] broadcast read (conflict-free), x[i+l]
//    stride-1 (2-way, free), <=2 predicated contiguous dword stores direct
//    to global. No LDS image, no index decode, no divergent chains.
//  - LDS 512 B -> 8 blocks/CU (32 waves) for store-latency hiding.

#define DD 128
#define ROW_OUT (DD + DD * (DD + 1) / 2) /* 8384 */

__global__ __launch_bounds__(256) void poly_kernel(
    const float* __restrict__ x, const float* __restrict__ scales,
    float* __restrict__ out) {
  __shared__ float s_x[DD];

  const int row = blockIdx.x;
  const int tid = threadIdx.x;
  const int w = tid >> 6;     // wave 0..3
  const int lane = tid & 63;  // lane in wave

  const float* xr = x + (size_t)row * DD;
  const float a = xr[lane];
  const float b = xr[lane + 64];

  if (w == 0) {  // stage raw row once
    s_x[lane] = a;
    s_x[lane + 64] = b;
  }

  // Every wave reduces ||x||^2 itself (no cross-wave broadcast needed).
  float p = a * a + b * b;
#pragma unroll
  for (int off = 32; off >= 1; off >>= 1) p += __shfl_xor(p, off, 64);

  const float c1 = 1.0f / fmaxf(sqrtf(p), 1e-12f);
  const float c2 = c1 * c1 * scales[1];

  float* orow = out + (size_t)row * ROW_OUT;
  if (w == 1) {  // degree-1 features
    orow[lane] = a * c1;
    orow[lane + 64] = b * c1;
  }
  __syncthreads();

  // Triangle runs: run i has len = 128-i elements at base DD + i*(257-i)/2.
#pragma unroll 4
  for (int i = w; i < DD; i += 4) {
    const float xi = s_x[i] * c2;  // wave-uniform broadcast
    const int len = DD - i;
    float* dst = orow + DD + ((i * (2 * DD + 1 - i)) >> 1);
    if (lane < len) dst[lane] = xi * s_x[i + lane];
    const int l2 = lane + 64;
    if (l2 < len) dst[l2] = xi * s_x[i + l2];
  }
}

extern "C" void kernel_launch(void* const* d_in, const int* in_sizes, int n_in,
                              void* d_out, int out_size, void* d_ws,
                              size_t ws_size, hipStream_t stream) {
  const float* x = (const float*)d_in[0];
  const float* scales = (const float*)d_in[1];
  float* out = (float*)d_out;
  const int n_rows = in_sizes[0] / DD;  // 8192
  poly_kernel<<<n_rows, 256, 0, stream>>>(x, scales, out);
}